// Round 1
// baseline (1123.079 us; speedup 1.0000x reference)
//
#include <hip/hip_runtime.h>

#define F128 128
#define EPSV 1e-12f

// ---------------- CSR build ----------------
__global__ void hist_kernel(const int* __restrict__ row, int* __restrict__ counts, int E) {
  int i = blockIdx.x * blockDim.x + threadIdx.x;
  int stride = gridDim.x * blockDim.x;
  for (; i < E; i += stride) atomicAdd(&counts[row[i]], 1);
}

__global__ __launch_bounds__(1024) void scan_kernel(const int* __restrict__ counts,
                                                    int* __restrict__ row_ptr,
                                                    int* __restrict__ fill, int n) {
  __shared__ int buf[1024];
  int t = threadIdx.x;
  int carry = 0;
  if (t == 0) row_ptr[0] = 0;
  for (int base = 0; base < n; base += 1024) {
    int i = base + t;
    int v = (i < n) ? counts[i] : 0;
    buf[t] = v;
    __syncthreads();
    for (int off = 1; off < 1024; off <<= 1) {
      int add = (t >= off) ? buf[t - off] : 0;
      __syncthreads();
      buf[t] += add;
      __syncthreads();
    }
    if (i < n) {
      int incl = buf[t];
      row_ptr[i + 1] = carry + incl;
      fill[i] = carry + incl - v;  // exclusive prefix
    }
    carry += buf[1023];
    __syncthreads();
  }
}

__global__ void scatter_kernel(const int* __restrict__ row, const int* __restrict__ col,
                               const float* __restrict__ val, int* __restrict__ fill,
                               int* __restrict__ scol, float* __restrict__ sval, int E) {
  int i = blockIdx.x * blockDim.x + threadIdx.x;
  int stride = gridDim.x * blockDim.x;
  for (; i < E; i += stride) {
    int r = row[i];
    int pos = atomicAdd(&fill[r], 1);
    scol[pos] = col[i];
    sval[pos] = val[i];
  }
}

// ---------------- SpMV: one wave per row, float2 per lane ----------------
__global__ __launch_bounds__(256) void spmv_kernel(const int* __restrict__ row_ptr,
                                                   const int* __restrict__ scol,
                                                   const float* __restrict__ sval,
                                                   const float* __restrict__ v,
                                                   float* __restrict__ w, int N) {
  int wid = (blockIdx.x * blockDim.x + threadIdx.x) >> 6;
  if (wid >= N) return;
  int lane = threadIdx.x & 63;
  int beg = row_ptr[wid], end = row_ptr[wid + 1];
  float accx = 0.f, accy = 0.f;
  for (int e = beg; e < end; ++e) {
    float val = sval[e];
    int c = scol[e];
    float2 vv = *(const float2*)&v[(size_t)c * F128 + lane * 2];
    accx += val * vv.x;
    accy += val * vv.y;
  }
  float2 o; o.x = accx; o.y = accy;
  *(float2*)&w[(size_t)wid * F128 + lane * 2] = o;
}

// ---------------- column reductions (sumsq / dot) ----------------
template <int DOT>
__global__ __launch_bounds__(256) void col_reduce_kernel(const float* __restrict__ a,
                                                         const float* __restrict__ b,
                                                         float* __restrict__ out, int nrows) {
  int t = threadIdx.x;
  int f0 = (t & 31) * 4;
  int rslot = blockIdx.x * 8 + (t >> 5);
  int rstride = gridDim.x * 8;
  float4 acc = make_float4(0.f, 0.f, 0.f, 0.f);
  for (int r = rslot; r < nrows; r += rstride) {
    size_t idx = (size_t)r * F128 + f0;
    float4 av = *(const float4*)&a[idx];
    if (DOT) {
      float4 bv = *(const float4*)&b[idx];
      acc.x += av.x * bv.x; acc.y += av.y * bv.y;
      acc.z += av.z * bv.z; acc.w += av.w * bv.w;
    } else {
      acc.x += av.x * av.x; acc.y += av.y * av.y;
      acc.z += av.z * av.z; acc.w += av.w * av.w;
    }
  }
  __shared__ float4 red[256];
  red[t] = acc;
  __syncthreads();
  if (t < 32) {
    float4 s = red[t];
#pragma unroll
    for (int j = 1; j < 8; ++j) {
      float4 o = red[t + 32 * j];
      s.x += o.x; s.y += o.y; s.z += o.z; s.w += o.w;
    }
    atomicAdd(&out[t * 4 + 0], s.x);
    atomicAdd(&out[t * 4 + 1], s.y);
    atomicAdd(&out[t * 4 + 2], s.z);
    atomicAdd(&out[t * 4 + 3], s.w);
  }
}

// ---------------- v0 = x * rsqrt(max(colnorm, eps)) ----------------
__global__ void v0norm_kernel(const float* __restrict__ x, const float* __restrict__ norms,
                              float* __restrict__ v0, int nquads) {
  int i = blockIdx.x * blockDim.x + threadIdx.x;
  int stride = gridDim.x * blockDim.x;
  for (; i < nquads; i += stride) {
    int f0 = (i * 4) & (F128 - 1);
    float4 nv = *(const float4*)&norms[f0];
    float4 xv = *(const float4*)&x[(size_t)i * 4];
    float4 o;
    o.x = xv.x / sqrtf(fmaxf(nv.x, EPSV));
    o.y = xv.y / sqrtf(fmaxf(nv.y, EPSV));
    o.z = xv.z / sqrtf(fmaxf(nv.z, EPSV));
    o.w = xv.w / sqrtf(fmaxf(nv.w, EPSV));
    *(float4*)&v0[(size_t)i * 4] = o;
  }
}

// ---------------- new_v = w - alpha*v_prev - beta_prev*v_prev2 ; betasq += new_v^2 ----------------
template <int HAS_PREV>
__global__ __launch_bounds__(256) void newv_kernel(float* __restrict__ w,
                                                   const float* __restrict__ vp,
                                                   const float* __restrict__ vp2,
                                                   const float* __restrict__ alpha,
                                                   const float* __restrict__ bsq_prev,
                                                   float* __restrict__ bsq_out, int nrows) {
  int t = threadIdx.x;
  int f0 = (t & 31) * 4;
  int rslot = blockIdx.x * 8 + (t >> 5);
  int rstride = gridDim.x * 8;
  float4 a = *(const float4*)&alpha[f0];
  float4 bp = make_float4(0.f, 0.f, 0.f, 0.f);
  if (HAS_PREV) {
    float4 b = *(const float4*)&bsq_prev[f0];
    bp.x = sqrtf(b.x); bp.y = sqrtf(b.y); bp.z = sqrtf(b.z); bp.w = sqrtf(b.w);
  }
  float4 acc = make_float4(0.f, 0.f, 0.f, 0.f);
  for (int r = rslot; r < nrows; r += rstride) {
    size_t idx = (size_t)r * F128 + f0;
    float4 wv = *(const float4*)&w[idx];
    float4 pv = *(const float4*)&vp[idx];
    wv.x -= a.x * pv.x; wv.y -= a.y * pv.y;
    wv.z -= a.z * pv.z; wv.w -= a.w * pv.w;
    if (HAS_PREV) {
      float4 p2 = *(const float4*)&vp2[idx];
      wv.x -= bp.x * p2.x; wv.y -= bp.y * p2.y;
      wv.z -= bp.z * p2.z; wv.w -= bp.w * p2.w;
    }
    *(float4*)&w[idx] = wv;
    acc.x += wv.x * wv.x; acc.y += wv.y * wv.y;
    acc.z += wv.z * wv.z; acc.w += wv.w * wv.w;
  }
  __shared__ float4 red[256];
  red[t] = acc;
  __syncthreads();
  if (t < 32) {
    float4 s = red[t];
#pragma unroll
    for (int j = 1; j < 8; ++j) {
      float4 o = red[t + 32 * j];
      s.x += o.x; s.y += o.y; s.z += o.z; s.w += o.w;
    }
    atomicAdd(&bsq_out[t * 4 + 0], s.x);
    atomicAdd(&bsq_out[t * 4 + 1], s.y);
    atomicAdd(&bsq_out[t * 4 + 2], s.z);
    atomicAdd(&bsq_out[t * 4 + 3], s.w);
  }
}

// ---------------- v = new_v / sqrt(betasq) ----------------
__global__ void vnorm_kernel(float* __restrict__ v, const float* __restrict__ bsq, int nquads) {
  int i = blockIdx.x * blockDim.x + threadIdx.x;
  int stride = gridDim.x * blockDim.x;
  for (; i < nquads; i += stride) {
    int f0 = (i * 4) & (F128 - 1);
    float4 b = *(const float4*)&bsq[f0];
    float4 xv = *(float4*)&v[(size_t)i * 4];
    xv.x /= sqrtf(b.x);
    xv.y /= sqrtf(b.y);
    xv.z /= sqrtf(b.z);
    xv.w /= sqrtf(b.w);
    *(float4*)&v[(size_t)i * 4] = xv;
  }
}

// ---------------- out += V @ W_k  (optionally relu at the end) ----------------
template <int RELU>
__global__ __launch_bounds__(256) void gemm_acc_kernel(float* __restrict__ out,
                                                       const float* __restrict__ V,
                                                       const float* __restrict__ W, int nrows) {
  __shared__ float Vl[16][F128];
  int t = threadIdx.x;
  int d0 = (t & 31) * 4;
  int rg = t >> 5;  // 0..7
  int ntiles = (nrows + 15) / 16;
  for (int tile = blockIdx.x; tile < ntiles; tile += gridDim.x) {
    int row0 = tile * 16;
    for (int i = t; i < 16 * 32; i += 256) {
      int rr = i >> 5, ff = (i & 31) * 4;
      float4 xv = make_float4(0.f, 0.f, 0.f, 0.f);
      if (row0 + rr < nrows) xv = *(const float4*)&V[(size_t)(row0 + rr) * F128 + ff];
      *(float4*)&Vl[rr][ff] = xv;
    }
    __syncthreads();
    float4 acc0 = make_float4(0.f, 0.f, 0.f, 0.f);
    float4 acc1 = make_float4(0.f, 0.f, 0.f, 0.f);
    int r0 = rg * 2, r1 = rg * 2 + 1;
#pragma unroll 4
    for (int f = 0; f < F128; ++f) {
      float4 wv = *(const float4*)&W[f * F128 + d0];
      float va = Vl[r0][f];
      float vb = Vl[r1][f];
      acc0.x += va * wv.x; acc0.y += va * wv.y;
      acc0.z += va * wv.z; acc0.w += va * wv.w;
      acc1.x += vb * wv.x; acc1.y += vb * wv.y;
      acc1.z += vb * wv.z; acc1.w += vb * wv.w;
    }
    if (row0 + r0 < nrows) {
      size_t idx = (size_t)(row0 + r0) * F128 + d0;
      float4 o = *(float4*)&out[idx];
      o.x += acc0.x; o.y += acc0.y; o.z += acc0.z; o.w += acc0.w;
      if (RELU) {
        o.x = fmaxf(o.x, 0.f); o.y = fmaxf(o.y, 0.f);
        o.z = fmaxf(o.z, 0.f); o.w = fmaxf(o.w, 0.f);
      }
      *(float4*)&out[idx] = o;
    }
    if (row0 + r1 < nrows) {
      size_t idx = (size_t)(row0 + r1) * F128 + d0;
      float4 o = *(float4*)&out[idx];
      o.x += acc1.x; o.y += acc1.y; o.z += acc1.z; o.w += acc1.w;
      if (RELU) {
        o.x = fmaxf(o.x, 0.f); o.y = fmaxf(o.y, 0.f);
        o.z = fmaxf(o.z, 0.f); o.w = fmaxf(o.w, 0.f);
      }
      *(float4*)&out[idx] = o;
    }
    __syncthreads();
  }
}

extern "C" void kernel_launch(void* const* d_in, const int* in_sizes, int n_in,
                              void* d_out, int out_size, void* d_ws, size_t ws_size,
                              hipStream_t stream) {
  const float* x = (const float*)d_in[0];
  const float* edge_vals = (const float*)d_in[1];
  const float* weights = (const float*)d_in[2];
  const int* edge_row = (const int*)d_in[3];
  const int* edge_col = (const int*)d_in[4];

  const int N = in_sizes[0] / F128;
  const int E = in_sizes[1];
  const int K = in_sizes[2] / (F128 * F128);
  float* out = (float*)d_out;

  size_t nf = (size_t)N * F128;
  float* vA = (float*)d_ws;
  float* vB = vA + nf;
  float* vC = vB + nf;
  int* row_ptr = (int*)(vC + nf);
  int* fill = row_ptr + (N + 1);
  int* counts = fill + N;
  int* scol = counts + N;
  float* sval = (float*)(scol + E);
  float* norms = sval + E;         // 128
  float* alpha = norms + F128;     // up to 8 slots of 128
  float* betasq = alpha + 8 * F128;  // up to 8 slots of 128

  // zero-init: edge counts, scalar reduction targets, output accumulator
  hipMemsetAsync(counts, 0, (size_t)N * sizeof(int), stream);
  hipMemsetAsync(norms, 0, (size_t)(1 + 16) * F128 * sizeof(float), stream);
  hipMemsetAsync(d_out, 0, (size_t)out_size * sizeof(float), stream);

  // CSR build
  hist_kernel<<<1024, 256, 0, stream>>>(edge_row, counts, E);
  scan_kernel<<<1, 1024, 0, stream>>>(counts, row_ptr, fill, N);
  scatter_kernel<<<1024, 256, 0, stream>>>(edge_row, edge_col, edge_vals, fill, scol, sval, E);

  int ntiles = (N + 15) / 16;

  // v0 = l2-normalized columns of x
  col_reduce_kernel<0><<<512, 256, 0, stream>>>(x, nullptr, norms, N);
  v0norm_kernel<<<2048, 256, 0, stream>>>(x, norms, vA, (int)(nf / 4));
  if (K == 1) gemm_acc_kernel<1><<<ntiles, 256, 0, stream>>>(out, vA, weights, N);
  else        gemm_acc_kernel<0><<<ntiles, 256, 0, stream>>>(out, vA, weights, N);

  float* v_prev = vA;
  float* v_prev2 = vB;  // dummy in step 1 (never read: HAS_PREV=0)
  float* wbuf = vC;
  for (int s = 1; s < K; ++s) {
    float* alph = alpha + (size_t)(s - 1) * F128;
    float* bsq = betasq + (size_t)(s - 1) * F128;
    int spmv_blocks = (N * 64 + 255) / 256;
    spmv_kernel<<<spmv_blocks, 256, 0, stream>>>(row_ptr, scol, sval, v_prev, wbuf, N);
    col_reduce_kernel<1><<<512, 256, 0, stream>>>(wbuf, v_prev, alph, N);
    if (s == 1)
      newv_kernel<0><<<512, 256, 0, stream>>>(wbuf, v_prev, v_prev2, alph, nullptr, bsq, N);
    else
      newv_kernel<1><<<512, 256, 0, stream>>>(wbuf, v_prev, v_prev2, alph,
                                              betasq + (size_t)(s - 2) * F128, bsq, N);
    vnorm_kernel<<<2048, 256, 0, stream>>>(wbuf, bsq, (int)(nf / 4));
    const float* Wk = weights + (size_t)s * F128 * F128;
    if (s == K - 1) gemm_acc_kernel<1><<<ntiles, 256, 0, stream>>>(out, wbuf, Wk, N);
    else            gemm_acc_kernel<0><<<ntiles, 256, 0, stream>>>(out, wbuf, Wk, N);
    // rotate buffers: v_prev <- new v, v_prev2 <- old v_prev, wbuf <- freed buffer
    float* old2 = v_prev2;
    v_prev2 = v_prev;
    v_prev = wbuf;
    wbuf = old2;
  }
}

// Round 2
// 1020.110 us; speedup vs baseline: 1.1009x; 1.1009x over previous
//
#include <hip/hip_runtime.h>

#define F128 128
#define EPSV 1e-12f

// ---------------- CSR build ----------------
__global__ void hist_kernel(const int* __restrict__ row, int* __restrict__ counts, int E) {
  int i = blockIdx.x * blockDim.x + threadIdx.x;
  int stride = gridDim.x * blockDim.x;
  for (; i < E; i += stride) atomicAdd(&counts[row[i]], 1);
}

// local inclusive scan of 1024-element chunks; per-chunk totals to partials
__global__ __launch_bounds__(1024) void scan_local_kernel(const int* __restrict__ counts,
                                                          int* __restrict__ tmp,
                                                          int* __restrict__ partials, int n) {
  __shared__ int buf[1024];
  int t = threadIdx.x;
  int i = blockIdx.x * 1024 + t;
  int v = (i < n) ? counts[i] : 0;
  buf[t] = v;
  __syncthreads();
  for (int off = 1; off < 1024; off <<= 1) {
    int add = (t >= off) ? buf[t - off] : 0;
    __syncthreads();
    buf[t] += add;
    __syncthreads();
  }
  if (i < n) tmp[i] = buf[t];
  if (t == 1023) partials[blockIdx.x] = buf[1023];
}

// exclusive scan of block partials (nblk <= 256)
__global__ __launch_bounds__(256) void scan_part_kernel(const int* __restrict__ partials,
                                                        int* __restrict__ part_excl, int nblk) {
  __shared__ int buf[256];
  int t = threadIdx.x;
  int v = (t < nblk) ? partials[t] : 0;
  buf[t] = v;
  __syncthreads();
  for (int off = 1; off < 256; off <<= 1) {
    int add = (t >= off) ? buf[t - off] : 0;
    __syncthreads();
    buf[t] += add;
    __syncthreads();
  }
  if (t < nblk) part_excl[t] = buf[t] - v;
}

__global__ __launch_bounds__(1024) void scan_fin_kernel(const int* __restrict__ tmp,
                                                        const int* __restrict__ part_excl,
                                                        const int* __restrict__ counts,
                                                        int* __restrict__ row_ptr,
                                                        int* __restrict__ fill, int n) {
  int t = threadIdx.x;
  int i = blockIdx.x * 1024 + t;
  if (i < n) {
    int incl = tmp[i] + part_excl[blockIdx.x];
    row_ptr[i + 1] = incl;
    fill[i] = incl - counts[i];  // exclusive prefix
  }
  if (i == 0) row_ptr[0] = 0;
}

__global__ void scatter_kernel(const int* __restrict__ row, const int* __restrict__ col,
                               const float* __restrict__ val, int* __restrict__ fill,
                               int* __restrict__ scol, float* __restrict__ sval, int E) {
  int i = blockIdx.x * blockDim.x + threadIdx.x;
  int stride = gridDim.x * blockDim.x;
  for (; i < E; i += stride) {
    int r = row[i];
    int pos = atomicAdd(&fill[r], 1);
    scol[pos] = col[i];
    sval[pos] = val[i];
  }
}

// ---------------- SpMV: one wave per row, float2 per lane ----------------
// input u is UNNORMALIZED; output w = A @ (u * rsqrt(max(raw,eps))) i.e. fully normalized input
__global__ __launch_bounds__(256) void spmv_kernel(const int* __restrict__ row_ptr,
                                                   const int* __restrict__ scol,
                                                   const float* __restrict__ sval,
                                                   const float* __restrict__ u,
                                                   const float* __restrict__ raw, float eps,
                                                   float* __restrict__ w, int N) {
  int wid = (blockIdx.x * blockDim.x + threadIdx.x) >> 6;
  if (wid >= N) return;
  int lane = threadIdx.x & 63;
  float rin0 = rsqrtf(fmaxf(raw[lane * 2 + 0], eps));
  float rin1 = rsqrtf(fmaxf(raw[lane * 2 + 1], eps));
  int beg = row_ptr[wid], end = row_ptr[wid + 1];
  float accx = 0.f, accy = 0.f;
  for (int e = beg; e < end; ++e) {
    float val = sval[e];
    int c = scol[e];
    float2 vv = *(const float2*)&u[(size_t)c * F128 + lane * 2];
    accx += val * vv.x;
    accy += val * vv.y;
  }
  float2 o; o.x = accx * rin0; o.y = accy * rin1;
  *(float2*)&w[(size_t)wid * F128 + lane * 2] = o;
}

// ---------------- column sum of squares (for v0 scale) ----------------
__global__ __launch_bounds__(256) void colsq_kernel(const float* __restrict__ a,
                                                    float* __restrict__ out, int nrows) {
  int t = threadIdx.x;
  int f0 = (t & 31) * 4;
  int rslot = blockIdx.x * 8 + (t >> 5);
  int rstride = gridDim.x * 8;
  float4 acc = make_float4(0.f, 0.f, 0.f, 0.f);
  for (int r = rslot; r < nrows; r += rstride) {
    size_t idx = (size_t)r * F128 + f0;
    float4 av = *(const float4*)&a[idx];
    acc.x += av.x * av.x; acc.y += av.y * av.y;
    acc.z += av.z * av.z; acc.w += av.w * av.w;
  }
  __shared__ float4 red[256];
  red[t] = acc;
  __syncthreads();
  if (t < 32) {
    float4 s = red[t];
#pragma unroll
    for (int j = 1; j < 8; ++j) {
      float4 o = red[t + 32 * j];
      s.x += o.x; s.y += o.y; s.z += o.z; s.w += o.w;
    }
    atomicAdd(&out[t * 4 + 0], s.x);
    atomicAdd(&out[t * 4 + 1], s.y);
    atomicAdd(&out[t * 4 + 2], s.z);
    atomicAdd(&out[t * 4 + 3], s.w);
  }
}

// ---------------- alpha = sum_r w[r][f] * (u[r][f]*c[f]) ----------------
__global__ __launch_bounds__(256) void coldot_kernel(const float* __restrict__ w,
                                                     const float* __restrict__ u,
                                                     const float* __restrict__ raw, float eps,
                                                     float* __restrict__ out, int nrows) {
  int t = threadIdx.x;
  int f0 = (t & 31) * 4;
  int rslot = blockIdx.x * 8 + (t >> 5);
  int rstride = gridDim.x * 8;
  float4 rw = *(const float4*)&raw[f0];
  float4 c;
  c.x = rsqrtf(fmaxf(rw.x, eps)); c.y = rsqrtf(fmaxf(rw.y, eps));
  c.z = rsqrtf(fmaxf(rw.z, eps)); c.w = rsqrtf(fmaxf(rw.w, eps));
  float4 acc = make_float4(0.f, 0.f, 0.f, 0.f);
  for (int r = rslot; r < nrows; r += rstride) {
    size_t idx = (size_t)r * F128 + f0;
    float4 wv = *(const float4*)&w[idx];
    float4 uv = *(const float4*)&u[idx];
    acc.x += wv.x * uv.x * c.x; acc.y += wv.y * uv.y * c.y;
    acc.z += wv.z * uv.z * c.z; acc.w += wv.w * uv.w * c.w;
  }
  __shared__ float4 red[256];
  red[t] = acc;
  __syncthreads();
  if (t < 32) {
    float4 s = red[t];
#pragma unroll
    for (int j = 1; j < 8; ++j) {
      float4 o = red[t + 32 * j];
      s.x += o.x; s.y += o.y; s.z += o.z; s.w += o.w;
    }
    atomicAdd(&out[t * 4 + 0], s.x);
    atomicAdd(&out[t * 4 + 1], s.y);
    atomicAdd(&out[t * 4 + 2], s.z);
    atomicAdd(&out[t * 4 + 3], s.w);
  }
}

// ---------------- u_new = w - alpha*(u_prev*c_prev) - beta_prev*(u_prev2*c_prev2) ; bsq += u_new^2
// w is overwritten in place with u_new (unnormalized). c_prev = rsqrt(max(prev_raw,prev_eps)).
// beta_prev = sqrt(prev_raw) (only when HAS_PREV; prev vector is then a Lanczos vector, prev_eps=0).
template <int HAS_PREV>
__global__ __launch_bounds__(256) void newv_kernel(float* __restrict__ w,
                                                   const float* __restrict__ up,
                                                   const float* __restrict__ up2,
                                                   const float* __restrict__ alpha,
                                                   const float* __restrict__ prev_raw, float prev_eps,
                                                   const float* __restrict__ prev2_raw, float prev2_eps,
                                                   float* __restrict__ bsq_out, int nrows) {
  int t = threadIdx.x;
  int f0 = (t & 31) * 4;
  int rslot = blockIdx.x * 8 + (t >> 5);
  int rstride = gridDim.x * 8;
  float4 a = *(const float4*)&alpha[f0];
  float4 pr = *(const float4*)&prev_raw[f0];
  float4 cp;
  cp.x = rsqrtf(fmaxf(pr.x, prev_eps)); cp.y = rsqrtf(fmaxf(pr.y, prev_eps));
  cp.z = rsqrtf(fmaxf(pr.z, prev_eps)); cp.w = rsqrtf(fmaxf(pr.w, prev_eps));
  // fold: term1 coeff = alpha * c_prev
  float4 ac;
  ac.x = a.x * cp.x; ac.y = a.y * cp.y; ac.z = a.z * cp.z; ac.w = a.w * cp.w;
  float4 g = make_float4(0.f, 0.f, 0.f, 0.f);
  if (HAS_PREV) {
    float4 p2 = *(const float4*)&prev2_raw[f0];
    g.x = sqrtf(pr.x) * rsqrtf(fmaxf(p2.x, prev2_eps));
    g.y = sqrtf(pr.y) * rsqrtf(fmaxf(p2.y, prev2_eps));
    g.z = sqrtf(pr.z) * rsqrtf(fmaxf(p2.z, prev2_eps));
    g.w = sqrtf(pr.w) * rsqrtf(fmaxf(p2.w, prev2_eps));
  }
  float4 acc = make_float4(0.f, 0.f, 0.f, 0.f);
  for (int r = rslot; r < nrows; r += rstride) {
    size_t idx = (size_t)r * F128 + f0;
    float4 wv = *(const float4*)&w[idx];
    float4 pv = *(const float4*)&up[idx];
    wv.x -= ac.x * pv.x; wv.y -= ac.y * pv.y;
    wv.z -= ac.z * pv.z; wv.w -= ac.w * pv.w;
    if (HAS_PREV) {
      float4 q = *(const float4*)&up2[idx];
      wv.x -= g.x * q.x; wv.y -= g.y * q.y;
      wv.z -= g.z * q.z; wv.w -= g.w * q.w;
    }
    *(float4*)&w[idx] = wv;
    acc.x += wv.x * wv.x; acc.y += wv.y * wv.y;
    acc.z += wv.z * wv.z; acc.w += wv.w * wv.w;
  }
  __shared__ float4 red[256];
  red[t] = acc;
  __syncthreads();
  if (t < 32) {
    float4 s = red[t];
#pragma unroll
    for (int j = 1; j < 8; ++j) {
      float4 o = red[t + 32 * j];
      s.x += o.x; s.y += o.y; s.z += o.z; s.w += o.w;
    }
    atomicAdd(&bsq_out[t * 4 + 0], s.x);
    atomicAdd(&bsq_out[t * 4 + 1], s.y);
    atomicAdd(&bsq_out[t * 4 + 2], s.z);
    atomicAdd(&bsq_out[t * 4 + 3], s.w);
  }
}

// ---------------- out += (U*c) @ W_k  (optionally relu at the end) ----------------
template <int RELU>
__global__ __launch_bounds__(256) void gemm_acc_kernel(float* __restrict__ out,
                                                       const float* __restrict__ U,
                                                       const float* __restrict__ raw, float eps,
                                                       const float* __restrict__ W, int nrows) {
  __shared__ float Vl[16][F128];
  int t = threadIdx.x;
  int d0 = (t & 31) * 4;
  int rg = t >> 5;  // 0..7
  int ntiles = (nrows + 15) / 16;
  for (int tile = blockIdx.x; tile < ntiles; tile += gridDim.x) {
    int row0 = tile * 16;
    for (int i = t; i < 16 * 32; i += 256) {
      int rr = i >> 5, ff = (i & 31) * 4;
      float4 xv = make_float4(0.f, 0.f, 0.f, 0.f);
      if (row0 + rr < nrows) {
        xv = *(const float4*)&U[(size_t)(row0 + rr) * F128 + ff];
        float4 rw = *(const float4*)&raw[ff];
        xv.x *= rsqrtf(fmaxf(rw.x, eps));
        xv.y *= rsqrtf(fmaxf(rw.y, eps));
        xv.z *= rsqrtf(fmaxf(rw.z, eps));
        xv.w *= rsqrtf(fmaxf(rw.w, eps));
      }
      *(float4*)&Vl[rr][ff] = xv;
    }
    __syncthreads();
    float4 acc0 = make_float4(0.f, 0.f, 0.f, 0.f);
    float4 acc1 = make_float4(0.f, 0.f, 0.f, 0.f);
    int r0 = rg * 2, r1 = rg * 2 + 1;
#pragma unroll 4
    for (int f = 0; f < F128; ++f) {
      float4 wv = *(const float4*)&W[f * F128 + d0];
      float va = Vl[r0][f];
      float vb = Vl[r1][f];
      acc0.x += va * wv.x; acc0.y += va * wv.y;
      acc0.z += va * wv.z; acc0.w += va * wv.w;
      acc1.x += vb * wv.x; acc1.y += vb * wv.y;
      acc1.z += vb * wv.z; acc1.w += vb * wv.w;
    }
    if (row0 + r0 < nrows) {
      size_t idx = (size_t)(row0 + r0) * F128 + d0;
      float4 o = *(float4*)&out[idx];
      o.x += acc0.x; o.y += acc0.y; o.z += acc0.z; o.w += acc0.w;
      if (RELU) {
        o.x = fmaxf(o.x, 0.f); o.y = fmaxf(o.y, 0.f);
        o.z = fmaxf(o.z, 0.f); o.w = fmaxf(o.w, 0.f);
      }
      *(float4*)&out[idx] = o;
    }
    if (row0 + r1 < nrows) {
      size_t idx = (size_t)(row0 + r1) * F128 + d0;
      float4 o = *(float4*)&out[idx];
      o.x += acc1.x; o.y += acc1.y; o.z += acc1.z; o.w += acc1.w;
      if (RELU) {
        o.x = fmaxf(o.x, 0.f); o.y = fmaxf(o.y, 0.f);
        o.z = fmaxf(o.z, 0.f); o.w = fmaxf(o.w, 0.f);
      }
      *(float4*)&out[idx] = o;
    }
    __syncthreads();
  }
}

extern "C" void kernel_launch(void* const* d_in, const int* in_sizes, int n_in,
                              void* d_out, int out_size, void* d_ws, size_t ws_size,
                              hipStream_t stream) {
  const float* x = (const float*)d_in[0];
  const float* edge_vals = (const float*)d_in[1];
  const float* weights = (const float*)d_in[2];
  const int* edge_row = (const int*)d_in[3];
  const int* edge_col = (const int*)d_in[4];

  const int N = in_sizes[0] / F128;
  const int E = in_sizes[1];
  const int K = in_sizes[2] / (F128 * F128);
  float* out = (float*)d_out;

  size_t nf = (size_t)N * F128;
  float* vbufs = (float*)d_ws;  // (K-1) buffers of nf (u_1..u_{K-1}); u_0 = x
  int* row_ptr = (int*)(vbufs + (size_t)(K - 1) * nf);
  int* fill = row_ptr + (N + 1);
  int* counts = fill + N;
  int* tmp = counts + N;
  int* partials = tmp + N;        // <=256
  int* part_excl = partials + 256;
  int* scol = part_excl + 256;
  float* sval = (float*)(scol + E);
  float* norms = sval + E;           // 128 (col sumsq of x)
  float* alpha = norms + F128;       // 8 slots of 128
  float* betasq = alpha + 8 * F128;  // 8 slots of 128

  // zero-init: edge counts, reduction targets, output accumulator
  hipMemsetAsync(counts, 0, (size_t)N * sizeof(int), stream);
  hipMemsetAsync(norms, 0, (size_t)(1 + 16) * F128 * sizeof(float), stream);
  hipMemsetAsync(d_out, 0, (size_t)out_size * sizeof(float), stream);

  // CSR build
  int nblk = (N + 1023) / 1024;  // 49 for N=50000 (must be <=256)
  hist_kernel<<<1024, 256, 0, stream>>>(edge_row, counts, E);
  scan_local_kernel<<<nblk, 1024, 0, stream>>>(counts, tmp, partials, N);
  scan_part_kernel<<<1, 256, 0, stream>>>(partials, part_excl, nblk);
  scan_fin_kernel<<<nblk, 1024, 0, stream>>>(tmp, part_excl, counts, row_ptr, fill, N);
  scatter_kernel<<<1024, 256, 0, stream>>>(edge_row, edge_col, edge_vals, fill, scol, sval, E);

  int ntiles = (N + 15) / 16;
  int spmv_blocks = (N * 64 + 255) / 256;

  // column sumsq of x -> scale for v0
  colsq_kernel<<<512, 256, 0, stream>>>(x, norms, N);
  if (K == 1) gemm_acc_kernel<1><<<ntiles, 256, 0, stream>>>(out, x, norms, EPSV, weights, N);
  else        gemm_acc_kernel<0><<<ntiles, 256, 0, stream>>>(out, x, norms, EPSV, weights, N);

  const float* u_prev = x;       // u_{s-1}
  const float* u_prev2 = nullptr;
  const float* praw = norms;     // raw for u_{s-1}
  float peps = EPSV;
  const float* p2raw = nullptr;
  float p2eps = 0.f;
  for (int s = 1; s < K; ++s) {
    float* ubuf = vbufs + (size_t)(s - 1) * nf;  // receives w then u_s in place
    float* alph = alpha + (size_t)(s - 1) * F128;
    float* bsq = betasq + (size_t)(s - 1) * F128;

    spmv_kernel<<<spmv_blocks, 256, 0, stream>>>(row_ptr, scol, sval, u_prev, praw, peps, ubuf, N);
    coldot_kernel<<<512, 256, 0, stream>>>(ubuf, u_prev, praw, peps, alph, N);
    if (s == 1)
      newv_kernel<0><<<512, 256, 0, stream>>>(ubuf, u_prev, nullptr, alph, praw, peps,
                                              nullptr, 0.f, bsq, N);
    else
      newv_kernel<1><<<512, 256, 0, stream>>>(ubuf, u_prev, u_prev2, alph, praw, peps,
                                              p2raw, p2eps, bsq, N);
    const float* Wk = weights + (size_t)s * F128 * F128;
    if (s == K - 1) gemm_acc_kernel<1><<<ntiles, 256, 0, stream>>>(out, ubuf, bsq, 0.f, Wk, N);
    else            gemm_acc_kernel<0><<<ntiles, 256, 0, stream>>>(out, ubuf, bsq, 0.f, Wk, N);

    // shift generations
    u_prev2 = u_prev; p2raw = praw; p2eps = peps;
    u_prev = ubuf;    praw = bsq;   peps = 0.f;
  }
}

// Round 3
// 736.427 us; speedup vs baseline: 1.5250x; 1.3852x over previous
//
#include <hip/hip_runtime.h>

#define F128 128
#define EPSV 1e-12f

typedef short bf16x8 __attribute__((ext_vector_type(8)));
typedef float f32x4 __attribute__((ext_vector_type(4)));

static __device__ __forceinline__ unsigned short f2bf(float f) {
  unsigned u = __float_as_uint(f);
  u += 0x7FFF + ((u >> 16) & 1);  // round to nearest even
  return (unsigned short)(u >> 16);
}

// ---------------- CSR build ----------------
__global__ void hist_kernel(const int* __restrict__ row, int* __restrict__ counts, int E) {
  int i = blockIdx.x * blockDim.x + threadIdx.x;
  int stride = gridDim.x * blockDim.x;
  for (; i < E; i += stride) atomicAdd(&counts[row[i]], 1);
}

__global__ __launch_bounds__(1024) void scan_local_kernel(const int* __restrict__ counts,
                                                          int* __restrict__ tmp,
                                                          int* __restrict__ partials, int n) {
  __shared__ int buf[1024];
  int t = threadIdx.x;
  int i = blockIdx.x * 1024 + t;
  int v = (i < n) ? counts[i] : 0;
  buf[t] = v;
  __syncthreads();
  for (int off = 1; off < 1024; off <<= 1) {
    int add = (t >= off) ? buf[t - off] : 0;
    __syncthreads();
    buf[t] += add;
    __syncthreads();
  }
  if (i < n) tmp[i] = buf[t];
  if (t == 1023) partials[blockIdx.x] = buf[1023];
}

__global__ __launch_bounds__(256) void scan_part_kernel(const int* __restrict__ partials,
                                                        int* __restrict__ part_excl, int nblk) {
  __shared__ int buf[256];
  int t = threadIdx.x;
  int v = (t < nblk) ? partials[t] : 0;
  buf[t] = v;
  __syncthreads();
  for (int off = 1; off < 256; off <<= 1) {
    int add = (t >= off) ? buf[t - off] : 0;
    __syncthreads();
    buf[t] += add;
    __syncthreads();
  }
  if (t < nblk) part_excl[t] = buf[t] - v;
}

__global__ __launch_bounds__(1024) void scan_fin_kernel(const int* __restrict__ tmp,
                                                        const int* __restrict__ part_excl,
                                                        const int* __restrict__ counts,
                                                        int* __restrict__ row_ptr,
                                                        int* __restrict__ fill, int n) {
  int t = threadIdx.x;
  int i = blockIdx.x * 1024 + t;
  if (i < n) {
    int incl = tmp[i] + part_excl[blockIdx.x];
    row_ptr[i + 1] = incl;
    fill[i] = incl - counts[i];  // exclusive prefix
  }
  if (i == 0) row_ptr[0] = 0;
}

// edges packed: .x = col, .y = float bits of val
__global__ void scatter_kernel(const int* __restrict__ row, const int* __restrict__ col,
                               const float* __restrict__ val, int* __restrict__ fill,
                               int2* __restrict__ edges, int E) {
  int i = blockIdx.x * blockDim.x + threadIdx.x;
  int stride = gridDim.x * blockDim.x;
  for (; i < E; i += stride) {
    int r = row[i];
    int pos = atomicAdd(&fill[r], 1);
    edges[pos] = make_int2(col[i], __float_as_int(val[i]));
  }
}

// ---------------- SpMV: one wave per row, float2 per lane, 4-deep MLP ----------------
__global__ __launch_bounds__(256) void spmv_kernel(const int* __restrict__ row_ptr,
                                                   const int2* __restrict__ edges,
                                                   const float* __restrict__ u,
                                                   const float* __restrict__ raw, float eps,
                                                   float* __restrict__ w, int N) {
  int wid = (blockIdx.x * blockDim.x + threadIdx.x) >> 6;
  if (wid >= N) return;
  int lane = threadIdx.x & 63;
  float rin0 = rsqrtf(fmaxf(raw[lane * 2 + 0], eps));
  float rin1 = rsqrtf(fmaxf(raw[lane * 2 + 1], eps));
  int beg = row_ptr[wid], end = row_ptr[wid + 1];
  float ax0 = 0.f, ay0 = 0.f, ax1 = 0.f, ay1 = 0.f;
  float ax2 = 0.f, ay2 = 0.f, ax3 = 0.f, ay3 = 0.f;
  int e = beg;
  for (; e + 4 <= end; e += 4) {
    int2 e0 = edges[e + 0];
    int2 e1 = edges[e + 1];
    int2 e2 = edges[e + 2];
    int2 e3 = edges[e + 3];
    float2 v0 = *(const float2*)&u[(size_t)e0.x * F128 + lane * 2];
    float2 v1 = *(const float2*)&u[(size_t)e1.x * F128 + lane * 2];
    float2 v2 = *(const float2*)&u[(size_t)e2.x * F128 + lane * 2];
    float2 v3 = *(const float2*)&u[(size_t)e3.x * F128 + lane * 2];
    float s0 = __int_as_float(e0.y), s1 = __int_as_float(e1.y);
    float s2 = __int_as_float(e2.y), s3 = __int_as_float(e3.y);
    ax0 += s0 * v0.x; ay0 += s0 * v0.y;
    ax1 += s1 * v1.x; ay1 += s1 * v1.y;
    ax2 += s2 * v2.x; ay2 += s2 * v2.y;
    ax3 += s3 * v3.x; ay3 += s3 * v3.y;
  }
  for (; e < end; ++e) {
    int2 ee = edges[e];
    float2 vv = *(const float2*)&u[(size_t)ee.x * F128 + lane * 2];
    float ss = __int_as_float(ee.y);
    ax0 += ss * vv.x; ay0 += ss * vv.y;
  }
  float accx = (ax0 + ax1) + (ax2 + ax3);
  float accy = (ay0 + ay1) + (ay2 + ay3);
  float2 o; o.x = accx * rin0; o.y = accy * rin1;
  *(float2*)&w[(size_t)wid * F128 + lane * 2] = o;
}

// ---------------- column sum of squares (for v0 scale) ----------------
__global__ __launch_bounds__(256) void colsq_kernel(const float* __restrict__ a,
                                                    float* __restrict__ out, int nrows) {
  int t = threadIdx.x;
  int f0 = (t & 31) * 4;
  int rslot = blockIdx.x * 8 + (t >> 5);
  int rstride = gridDim.x * 8;
  float4 acc = make_float4(0.f, 0.f, 0.f, 0.f);
  for (int r = rslot; r < nrows; r += rstride) {
    size_t idx = (size_t)r * F128 + f0;
    float4 av = *(const float4*)&a[idx];
    acc.x += av.x * av.x; acc.y += av.y * av.y;
    acc.z += av.z * av.z; acc.w += av.w * av.w;
  }
  __shared__ float4 red[256];
  red[t] = acc;
  __syncthreads();
  if (t < 32) {
    float4 s = red[t];
#pragma unroll
    for (int j = 1; j < 8; ++j) {
      float4 o = red[t + 32 * j];
      s.x += o.x; s.y += o.y; s.z += o.z; s.w += o.w;
    }
    atomicAdd(&out[t * 4 + 0], s.x);
    atomicAdd(&out[t * 4 + 1], s.y);
    atomicAdd(&out[t * 4 + 2], s.z);
    atomicAdd(&out[t * 4 + 3], s.w);
  }
}

// ---------------- alpha[f] = sum_r w[r][f] * (u[r][f]*c[f]) ----------------
__global__ __launch_bounds__(256) void coldot_kernel(const float* __restrict__ w,
                                                     const float* __restrict__ u,
                                                     const float* __restrict__ raw, float eps,
                                                     float* __restrict__ out, int nrows) {
  int t = threadIdx.x;
  int f0 = (t & 31) * 4;
  int rslot = blockIdx.x * 8 + (t >> 5);
  int rstride = gridDim.x * 8;
  float4 rw = *(const float4*)&raw[f0];
  float4 c;
  c.x = rsqrtf(fmaxf(rw.x, eps)); c.y = rsqrtf(fmaxf(rw.y, eps));
  c.z = rsqrtf(fmaxf(rw.z, eps)); c.w = rsqrtf(fmaxf(rw.w, eps));
  float4 acc = make_float4(0.f, 0.f, 0.f, 0.f);
  for (int r = rslot; r < nrows; r += rstride) {
    size_t idx = (size_t)r * F128 + f0;
    float4 wv = *(const float4*)&w[idx];
    float4 uv = *(const float4*)&u[idx];
    acc.x += wv.x * uv.x * c.x; acc.y += wv.y * uv.y * c.y;
    acc.z += wv.z * uv.z * c.z; acc.w += wv.w * uv.w * c.w;
  }
  __shared__ float4 red[256];
  red[t] = acc;
  __syncthreads();
  if (t < 32) {
    float4 s = red[t];
#pragma unroll
    for (int j = 1; j < 8; ++j) {
      float4 o = red[t + 32 * j];
      s.x += o.x; s.y += o.y; s.z += o.z; s.w += o.w;
    }
    atomicAdd(&out[t * 4 + 0], s.x);
    atomicAdd(&out[t * 4 + 1], s.y);
    atomicAdd(&out[t * 4 + 2], s.z);
    atomicAdd(&out[t * 4 + 3], s.w);
  }
}

// ---------------- u_new = w - alpha*(u_prev*c_prev) - beta_prev*(u_prev2*c_prev2); bsq += u_new^2
template <int HAS_PREV>
__global__ __launch_bounds__(256) void newv_kernel(float* __restrict__ w,
                                                   const float* __restrict__ up,
                                                   const float* __restrict__ up2,
                                                   const float* __restrict__ alpha,
                                                   const float* __restrict__ prev_raw, float prev_eps,
                                                   const float* __restrict__ prev2_raw, float prev2_eps,
                                                   float* __restrict__ bsq_out, int nrows) {
  int t = threadIdx.x;
  int f0 = (t & 31) * 4;
  int rslot = blockIdx.x * 8 + (t >> 5);
  int rstride = gridDim.x * 8;
  float4 a = *(const float4*)&alpha[f0];
  float4 pr = *(const float4*)&prev_raw[f0];
  float4 cp;
  cp.x = rsqrtf(fmaxf(pr.x, prev_eps)); cp.y = rsqrtf(fmaxf(pr.y, prev_eps));
  cp.z = rsqrtf(fmaxf(pr.z, prev_eps)); cp.w = rsqrtf(fmaxf(pr.w, prev_eps));
  float4 ac;
  ac.x = a.x * cp.x; ac.y = a.y * cp.y; ac.z = a.z * cp.z; ac.w = a.w * cp.w;
  float4 g = make_float4(0.f, 0.f, 0.f, 0.f);
  if (HAS_PREV) {
    float4 p2 = *(const float4*)&prev2_raw[f0];
    g.x = sqrtf(pr.x) * rsqrtf(fmaxf(p2.x, prev2_eps));
    g.y = sqrtf(pr.y) * rsqrtf(fmaxf(p2.y, prev2_eps));
    g.z = sqrtf(pr.z) * rsqrtf(fmaxf(p2.z, prev2_eps));
    g.w = sqrtf(pr.w) * rsqrtf(fmaxf(p2.w, prev2_eps));
  }
  float4 acc = make_float4(0.f, 0.f, 0.f, 0.f);
  for (int r = rslot; r < nrows; r += rstride) {
    size_t idx = (size_t)r * F128 + f0;
    float4 wv = *(const float4*)&w[idx];
    float4 pv = *(const float4*)&up[idx];
    wv.x -= ac.x * pv.x; wv.y -= ac.y * pv.y;
    wv.z -= ac.z * pv.z; wv.w -= ac.w * pv.w;
    if (HAS_PREV) {
      float4 q = *(const float4*)&up2[idx];
      wv.x -= g.x * q.x; wv.y -= g.y * q.y;
      wv.z -= g.z * q.z; wv.w -= g.w * q.w;
    }
    *(float4*)&w[idx] = wv;
    acc.x += wv.x * wv.x; acc.y += wv.y * wv.y;
    acc.z += wv.z * wv.z; acc.w += wv.w * wv.w;
  }
  __shared__ float4 red[256];
  red[t] = acc;
  __syncthreads();
  if (t < 32) {
    float4 s = red[t];
#pragma unroll
    for (int j = 1; j < 8; ++j) {
      float4 o = red[t + 32 * j];
      s.x += o.x; s.y += o.y; s.z += o.z; s.w += o.w;
    }
    atomicAdd(&bsq_out[t * 4 + 0], s.x);
    atomicAdd(&bsq_out[t * 4 + 1], s.y);
    atomicAdd(&bsq_out[t * 4 + 2], s.z);
    atomicAdd(&bsq_out[t * 4 + 3], s.w);
  }
}

// ---------------- W prep: fold per-column scale into W, emit bf16 MFMA B-frag layout ----------
// B-frag layout for 16x16x32: lane = (kin>>3)*16 | (d&15), elem j = kin&7, ctile = d>>4
// wfrag[((kstep*8 + ctile)*64 + lane)*8 + j]
__global__ void wprep_kernel(const float* __restrict__ weights,
                             const float* __restrict__ norms,
                             const float* __restrict__ betasq,
                             unsigned short* __restrict__ wfrag, int total) {
  int t = blockIdx.x * blockDim.x + threadIdx.x;
  if (t >= total) return;
  int k = t >> 14;          // F128*F128 = 16384
  int f = (t >> 7) & 127;
  int d = t & 127;
  float c = (k == 0) ? rsqrtf(fmaxf(norms[f], EPSV)) : rsqrtf(betasq[(k - 1) * F128 + f]);
  float val = weights[t] * c;
  int Kidx = k * F128 + f;
  int kstep = Kidx >> 5, kin = Kidx & 31;
  int lane = ((kin >> 3) << 4) | (d & 15);
  int ct = d >> 4, j = kin & 7;
  wfrag[(((kstep * 8 + ct) * 64 + lane) << 3) | j] = f2bf(val);
}

// ---------------- fused MFMA GEMM: out = relu(sum_k Vk @ Wk) ----------------
// one wave per 16-row tile; 4 waves per block; B-frags straight from global (L2-resident)
__global__ __launch_bounds__(256) void mfma_gemm_kernel(float* __restrict__ out,
                                                        const float* __restrict__ x,
                                                        const float* __restrict__ vbufs, size_t nf,
                                                        const unsigned short* __restrict__ wfrag,
                                                        int N, int K) {
  int wv = threadIdx.x >> 6, lane = threadIdx.x & 63;
  int n0 = blockIdx.x * 64 + wv * 16;
  if (n0 >= N) return;
  int rrow = n0 + (lane & 15);
  if (rrow >= N) rrow = N - 1;  // clamp: loads safe, stores guarded
  int khalf = lane >> 4;        // 0..3
  f32x4 acc[8];
#pragma unroll
  for (int i = 0; i < 8; ++i) acc[i] = (f32x4){0.f, 0.f, 0.f, 0.f};
  for (int k = 0; k < K; ++k) {
    const float* Uk = (k == 0) ? x : (vbufs + (size_t)(k - 1) * nf);
    const float* arow = Uk + (size_t)rrow * F128 + khalf * 8;
#pragma unroll
    for (int kk = 0; kk < 4; ++kk) {
      float4 a0 = *(const float4*)(arow + kk * 32);
      float4 a1 = *(const float4*)(arow + kk * 32 + 4);
      bf16x8 af;
      af[0] = (short)f2bf(a0.x); af[1] = (short)f2bf(a0.y);
      af[2] = (short)f2bf(a0.z); af[3] = (short)f2bf(a0.w);
      af[4] = (short)f2bf(a1.x); af[5] = (short)f2bf(a1.y);
      af[6] = (short)f2bf(a1.z); af[7] = (short)f2bf(a1.w);
      int kstep = k * 4 + kk;
      const unsigned short* bbase = wfrag + (((kstep * 8) * 64 + lane) << 3);
#pragma unroll
      for (int ct = 0; ct < 8; ++ct) {
        bf16x8 bfr = *(const bf16x8*)(bbase + (ct << 9));  // ct*64*8
        acc[ct] = __builtin_amdgcn_mfma_f32_16x16x32_bf16(af, bfr, acc[ct], 0, 0, 0);
      }
    }
  }
#pragma unroll
  for (int ct = 0; ct < 8; ++ct) {
#pragma unroll
    for (int j = 0; j < 4; ++j) {
      int r = n0 + khalf * 4 + j;
      if (r < N) out[(size_t)r * F128 + ct * 16 + (lane & 15)] = fmaxf(acc[ct][j], 0.f);
    }
  }
}

extern "C" void kernel_launch(void* const* d_in, const int* in_sizes, int n_in,
                              void* d_out, int out_size, void* d_ws, size_t ws_size,
                              hipStream_t stream) {
  const float* x = (const float*)d_in[0];
  const float* edge_vals = (const float*)d_in[1];
  const float* weights = (const float*)d_in[2];
  const int* edge_row = (const int*)d_in[3];
  const int* edge_col = (const int*)d_in[4];

  const int N = in_sizes[0] / F128;
  const int E = in_sizes[1];
  const int K = in_sizes[2] / (F128 * F128);
  float* out = (float*)d_out;

  size_t nf = (size_t)N * F128;
  float* vbufs = (float*)d_ws;  // (K-1) buffers of nf (u_1..u_{K-1}); u_0 = x
  unsigned short* wfrag = (unsigned short*)(vbufs + (size_t)(K - 1) * nf);
  int wtotal = K * F128 * F128;
  int* row_ptr = (int*)(wfrag + wtotal);  // N+2 (pad for alignment)
  int* fill = row_ptr + (N + 2);
  int* counts = fill + N;
  int* tmp = counts + N;
  int* partials = tmp + N;        // 256
  int* part_excl = partials + 256;
  int2* edges = (int2*)(part_excl + 256);
  float* norms = (float*)(edges + E);  // 128 (col sumsq of x)
  float* alpha = norms + F128;         // 8 slots of 128
  float* betasq = alpha + 8 * F128;    // 8 slots of 128

  hipMemsetAsync(counts, 0, (size_t)N * sizeof(int), stream);
  hipMemsetAsync(norms, 0, (size_t)(1 + 16) * F128 * sizeof(float), stream);

  // CSR build
  int nblk = (N + 1023) / 1024;  // must be <=256
  hist_kernel<<<1024, 256, 0, stream>>>(edge_row, counts, E);
  scan_local_kernel<<<nblk, 1024, 0, stream>>>(counts, tmp, partials, N);
  scan_part_kernel<<<1, 256, 0, stream>>>(partials, part_excl, nblk);
  scan_fin_kernel<<<nblk, 1024, 0, stream>>>(tmp, part_excl, counts, row_ptr, fill, N);
  scatter_kernel<<<1024, 256, 0, stream>>>(edge_row, edge_col, edge_vals, fill, edges, E);

  int spmv_blocks = (N * 64 + 255) / 256;

  // column sumsq of x -> scale for v0
  colsq_kernel<<<512, 256, 0, stream>>>(x, norms, N);

  const float* u_prev = x;
  const float* u_prev2 = nullptr;
  const float* praw = norms;
  float peps = EPSV;
  const float* p2raw = nullptr;
  float p2eps = 0.f;
  for (int s = 1; s < K; ++s) {
    float* ubuf = vbufs + (size_t)(s - 1) * nf;
    float* alph = alpha + (size_t)(s - 1) * F128;
    float* bsq = betasq + (size_t)(s - 1) * F128;

    spmv_kernel<<<spmv_blocks, 256, 0, stream>>>(row_ptr, edges, u_prev, praw, peps, ubuf, N);
    coldot_kernel<<<512, 256, 0, stream>>>(ubuf, u_prev, praw, peps, alph, N);
    if (s == 1)
      newv_kernel<0><<<512, 256, 0, stream>>>(ubuf, u_prev, nullptr, alph, praw, peps,
                                              nullptr, 0.f, bsq, N);
    else
      newv_kernel<1><<<512, 256, 0, stream>>>(ubuf, u_prev, u_prev2, alph, praw, peps,
                                              p2raw, p2eps, bsq, N);

    u_prev2 = u_prev; p2raw = praw; p2eps = peps;
    u_prev = ubuf;    praw = bsq;   peps = 0.f;
  }

  // fold scales into W (bf16, MFMA frag layout), then one fused MFMA GEMM + relu
  wprep_kernel<<<(wtotal + 255) / 256, 256, 0, stream>>>(weights, norms, betasq, wfrag, wtotal);
  mfma_gemm_kernel<<<(N + 63) / 64, 256, 0, stream>>>(out, x, vbufs, nf, wfrag, N, K);
}